// Round 5
// baseline (165.673 us; speedup 1.0000x reference)
//
#include <hip/hip_runtime.h>
#include <math.h>

#define DIM 128
#define TEMP_INV 10.0f
#define SPLIT 4               // blocks per anchor in the loss kernel

typedef __attribute__((ext_vector_type(2))) float floatx2;

// ---------------- fp8 fast path ----------------
// Normalize rows and quantize to fp8 e4m3 (OCP, HW cvt): one 32-lane group
// per row; lane holds 4 floats -> packs 4 fp8 into one uint.
// Also zeroes d_out[0] and the per-anchor partial arrays (harness re-poisons
// out/ws to 0xAA before every timed replay).
__global__ __launch_bounds__(256) void norm_fp8_kernel(const float* __restrict__ x,
                                                       unsigned int* __restrict__ xq,
                                                       float* __restrict__ partials,
                                                       int A3,
                                                       float* __restrict__ out,
                                                       int N) {
    int gtid = blockIdx.x * 256 + threadIdx.x;
    if (gtid == 0) out[0] = 0.0f;
    if (gtid < A3) partials[gtid] = 0.0f;

    int lane = threadIdx.x & 31;
    int grp  = threadIdx.x >> 5;
    int row  = blockIdx.x * 8 + grp;
    if (row >= N) return;
    float4 v = *(const float4*)(x + (size_t)row * DIM + lane * 4);
    float s = v.x*v.x + v.y*v.y + v.z*v.z + v.w*v.w;
    s += __shfl_xor(s, 16); s += __shfl_xor(s, 8); s += __shfl_xor(s, 4);
    s += __shfl_xor(s, 2);  s += __shfl_xor(s, 1);
    float inv = rsqrtf(s);
    int p = 0;
    p = __builtin_amdgcn_cvt_pk_fp8_f32(v.x * inv, v.y * inv, p, false);
    p = __builtin_amdgcn_cvt_pk_fp8_f32(v.z * inv, v.w * inv, p, true);
    xq[(size_t)row * 32 + lane] = (unsigned int)p;
}

static __device__ __forceinline__ float dot16_fp8(const uint4& r, const float* av) {
    floatx2 t;
    float d = 0.0f;
    t = __builtin_amdgcn_cvt_pk_f32_fp8((int)r.x, false); d += av[0]*t.x  + av[1]*t.y;
    t = __builtin_amdgcn_cvt_pk_f32_fp8((int)r.x, true);  d += av[2]*t.x  + av[3]*t.y;
    t = __builtin_amdgcn_cvt_pk_f32_fp8((int)r.y, false); d += av[4]*t.x  + av[5]*t.y;
    t = __builtin_amdgcn_cvt_pk_f32_fp8((int)r.y, true);  d += av[6]*t.x  + av[7]*t.y;
    t = __builtin_amdgcn_cvt_pk_f32_fp8((int)r.z, false); d += av[8]*t.x  + av[9]*t.y;
    t = __builtin_amdgcn_cvt_pk_f32_fp8((int)r.z, true);  d += av[10]*t.x + av[11]*t.y;
    t = __builtin_amdgcn_cvt_pk_f32_fp8((int)r.w, false); d += av[12]*t.x + av[13]*t.y;
    t = __builtin_amdgcn_cvt_pk_f32_fp8((int)r.w, true);  d += av[14]*t.x + av[15]*t.y;
    return d;
}

// Grid = A*SPLIT blocks; block handles S/SPLIT samples of anchor
// (blockIdx>>2), quarter (blockIdx&3). 256 thr = 32 groups of 8 lanes; lane
// loads uint4 = 16 fp8; 8 lanes cover the 128B row (one cache line). All 4
// iterations' loads issued up front (full unroll) -> 32 rows in flight/wave.
// Per-wave partial num/den/cnt atomicAdd'ed to ws arrays; finalize kernel
// does the log.
__global__ __launch_bounds__(256, 8) void loss_fp8_kernel(const unsigned int* __restrict__ xq,
                                                          const int* __restrict__ y,
                                                          const int* __restrict__ anchors,
                                                          const int* __restrict__ sampled,
                                                          float* __restrict__ p_num,
                                                          float* __restrict__ p_den,
                                                          float* __restrict__ p_cnt,
                                                          int S) {
    int a    = blockIdx.x >> 2;       // anchor
    int q    = blockIdx.x & 3;        // quarter
    int tid  = threadIdx.x;
    int lane = tid & 7;
    int grp  = tid >> 3;              // 0..31
    int spb  = S >> 2;                // samples per block (128)

    extern __shared__ int sm[];
    int* s_samp = sm;                 // [spb]
    int* s_y    = sm + spb;           // [spb]

    const int* samp = sampled + (size_t)a * S + (size_t)q * spb;
    for (int i = tid; i < spb; i += 256) {
        int si = samp[i];             // coalesced
        s_samp[i] = si;
        s_y[i] = y[si];               // divergent gather, L2-resident (400KB)
    }

    int anchor = anchors[a];
    int ya     = y[anchor];
    uint4 ar = *(const uint4*)(xq + (size_t)anchor * 32 + lane * 4);
    float av[16];
    {
        floatx2 t;
        t = __builtin_amdgcn_cvt_pk_f32_fp8((int)ar.x, false); av[0]=t.x;  av[1]=t.y;
        t = __builtin_amdgcn_cvt_pk_f32_fp8((int)ar.x, true);  av[2]=t.x;  av[3]=t.y;
        t = __builtin_amdgcn_cvt_pk_f32_fp8((int)ar.y, false); av[4]=t.x;  av[5]=t.y;
        t = __builtin_amdgcn_cvt_pk_f32_fp8((int)ar.y, true);  av[6]=t.x;  av[7]=t.y;
        t = __builtin_amdgcn_cvt_pk_f32_fp8((int)ar.z, false); av[8]=t.x;  av[9]=t.y;
        t = __builtin_amdgcn_cvt_pk_f32_fp8((int)ar.z, true);  av[10]=t.x; av[11]=t.y;
        t = __builtin_amdgcn_cvt_pk_f32_fp8((int)ar.w, false); av[12]=t.x; av[13]=t.y;
        t = __builtin_amdgcn_cvt_pk_f32_fp8((int)ar.w, true);  av[14]=t.x; av[15]=t.y;
#pragma unroll
        for (int j = 0; j < 16; ++j) av[j] *= TEMP_INV;   // fold 1/temp
    }
    __syncthreads();

    float num = 0.0f, den = 0.0f, cnt = 0.0f;
#pragma unroll
    for (int s = grp; s < 128; s += 32) {     // spb==128 (guarded on host)
        int sidx = s_samp[s];
        int ys   = s_y[s];
        uint4 sr = *(const uint4*)(xq + (size_t)sidx * 32 + lane * 4);
        float d = dot16_fp8(sr, av);
        d += __shfl_xor(d, 4); d += __shfl_xor(d, 2); d += __shfl_xor(d, 1);
        float e = __expf(d);                  // d = sim/temp already
        den += e;
        bool pos = (ys == ya);
        num += pos ? e : 0.0f;
        cnt += pos ? 1.0f : 0.0f;
    }

    // lanes within an 8-lane group identical; butterfly across the 8 groups
    num += __shfl_xor(num, 8);  den += __shfl_xor(den, 8);  cnt += __shfl_xor(cnt, 8);
    num += __shfl_xor(num, 16); den += __shfl_xor(den, 16); cnt += __shfl_xor(cnt, 16);
    num += __shfl_xor(num, 32); den += __shfl_xor(den, 32); cnt += __shfl_xor(cnt, 32);
    if ((tid & 63) == 0) {
        atomicAdd(p_num + a, num);
        atomicAdd(p_den + a, den);
        atomicAdd(p_cnt + a, cnt);
    }
}

// Per-anchor log + global sum. One thread per anchor.
__global__ __launch_bounds__(256) void finalize_kernel(const float* __restrict__ p_num,
                                                       const float* __restrict__ p_den,
                                                       const float* __restrict__ p_cnt,
                                                       float* __restrict__ out,
                                                       int A) {
    int a = blockIdx.x * 256 + threadIdx.x;
    float loss = 0.0f;
    if (a < A) {
        float tc = p_cnt[a];
        if (tc > 0.0f) loss = -__logf(p_num[a] / p_den[a]) / tc;
    }
    loss += __shfl_xor(loss, 1);  loss += __shfl_xor(loss, 2);
    loss += __shfl_xor(loss, 4);  loss += __shfl_xor(loss, 8);
    loss += __shfl_xor(loss, 16); loss += __shfl_xor(loss, 32);
    if ((threadIdx.x & 63) == 0) atomicAdd(out, loss);
}

// ---------------- fp32 fallback (used only if ws too small / odd shape) -----

__global__ __launch_bounds__(256) void norm_kernel(const float* __restrict__ x,
                                                   float* __restrict__ inv_norm,
                                                   float* __restrict__ out,
                                                   int N) {
    if (blockIdx.x == 0 && threadIdx.x == 0) out[0] = 0.0f;
    int wave = threadIdx.x >> 6;
    int lane = threadIdx.x & 63;
    int row  = blockIdx.x * 4 + wave;
    if (row >= N) return;
    const float2 v = *(const float2*)(x + (size_t)row * DIM + lane * 2);
    float s = v.x * v.x + v.y * v.y;
    s += __shfl_xor(s, 32); s += __shfl_xor(s, 16); s += __shfl_xor(s, 8);
    s += __shfl_xor(s, 4);  s += __shfl_xor(s, 2);  s += __shfl_xor(s, 1);
    if (lane == 0) inv_norm[row] = rsqrtf(s);
}

__global__ __launch_bounds__(256) void loss_kernel(const float* __restrict__ x,
                                                   const int* __restrict__ y,
                                                   const int* __restrict__ anchors,
                                                   const int* __restrict__ sampled,
                                                   const float* __restrict__ inv_norm,
                                                   float* __restrict__ out,
                                                   int S) {
    int a     = blockIdx.x;
    int tid   = threadIdx.x;
    int lane  = tid & 31;
    int group = tid >> 5;

    int   anchor = anchors[a];
    int   ya     = y[anchor];
    float inv_a  = inv_norm[anchor];
    float4 av = *(const float4*)(x + (size_t)anchor * DIM + lane * 4);
    av.x *= inv_a; av.y *= inv_a; av.z *= inv_a; av.w *= inv_a;

    float num = 0.0f, den = 0.0f, cnt = 0.0f;
    const int* samp = sampled + (size_t)a * S;

#pragma unroll 4
    for (int s = group; s < S; s += 8) {
        int   sidx  = samp[s];
        float inv_s = inv_norm[sidx];
        int   ys    = y[sidx];
        const float4 sv = *(const float4*)(x + (size_t)sidx * DIM + lane * 4);
        float d = av.x * sv.x + av.y * sv.y + av.z * sv.z + av.w * sv.w;
        d += __shfl_xor(d, 16); d += __shfl_xor(d, 8); d += __shfl_xor(d, 4);
        d += __shfl_xor(d, 2);  d += __shfl_xor(d, 1);
        float e = __expf(d * inv_s * TEMP_INV);
        den += e;
        bool pos = (ys == ya);
        num += pos ? e : 0.0f;
        cnt += pos ? 1.0f : 0.0f;
    }

    __shared__ float s_num[8], s_den[8], s_cnt[8];
    if (lane == 0) { s_num[group] = num; s_den[group] = den; s_cnt[group] = cnt; }
    __syncthreads();
    if (tid == 0) {
        float tn = 0.0f, td = 0.0f, tc = 0.0f;
        for (int g = 0; g < 8; ++g) { tn += s_num[g]; td += s_den[g]; tc += s_cnt[g]; }
        float loss = 0.0f;
        if (tc > 0.0f) loss = -__logf(tn / td) / tc;
        atomicAdd(out, loss);
    }
}

extern "C" void kernel_launch(void* const* d_in, const int* in_sizes, int n_in,
                              void* d_out, int out_size, void* d_ws, size_t ws_size,
                              hipStream_t stream) {
    const float* x       = (const float*)d_in[0];
    const int*   y       = (const int*)d_in[1];
    const int*   anchors = (const int*)d_in[2];
    const int*   sampled = (const int*)d_in[3];

    int N = in_sizes[1];
    int A = in_sizes[2];
    int S = in_sizes[3] / A;

    float* out = (float*)d_out;
    size_t need_fp8 = (size_t)N * DIM + (size_t)3 * A * sizeof(float);

    if (ws_size >= need_fp8 && S == 512) {
        unsigned int* xq = (unsigned int*)d_ws;
        float* partials  = (float*)((char*)d_ws + (size_t)N * DIM);
        float* p_num = partials;
        float* p_den = partials + A;
        float* p_cnt = partials + 2 * A;

        int nblocks = (N + 7) / 8;
        norm_fp8_kernel<<<nblocks, 256, 0, stream>>>(x, xq, partials, 3 * A, out, N);
        int spb = S / SPLIT;                       // 128
        size_t lds = 2 * (size_t)spb * sizeof(int);
        loss_fp8_kernel<<<A * SPLIT, 256, lds, stream>>>(xq, y, anchors, sampled,
                                                         p_num, p_den, p_cnt, S);
        finalize_kernel<<<(A + 255) / 256, 256, 0, stream>>>(p_num, p_den, p_cnt, out, A);
    } else {
        float* inv_norm = (float*)d_ws;
        int nblocks = (N + 3) / 4;
        norm_kernel<<<nblocks, 256, 0, stream>>>(x, inv_norm, out, N);
        loss_kernel<<<A, 256, 0, stream>>>(x, y, anchors, sampled, inv_norm, out, S);
    }
}

// Round 6
// 157.971 us; speedup vs baseline: 1.0488x; 1.0488x over previous
//
#include <hip/hip_runtime.h>
#include <math.h>

#define DIM 128
#define TEMP_INV 10.0f
#define SPLIT 4               // blocks per anchor in the loss kernel

typedef __attribute__((ext_vector_type(2))) float floatx2;

// ---------------- fp8 fast path ----------------
// Normalize rows and quantize to fp8 e4m3 (OCP, HW cvt): one 32-lane group
// per row; lane holds 4 floats -> packs 4 fp8 into one uint.
// Also zeroes d_out[0] and the per-anchor partial arrays (harness re-poisons
// out/ws to 0xAA before every timed replay).
__global__ __launch_bounds__(256) void norm_fp8_kernel(const float* __restrict__ x,
                                                       unsigned int* __restrict__ xq,
                                                       float* __restrict__ partials,
                                                       int A3,
                                                       float* __restrict__ out,
                                                       int N) {
    int gtid = blockIdx.x * 256 + threadIdx.x;
    if (gtid == 0) out[0] = 0.0f;
    if (gtid < A3) partials[gtid] = 0.0f;

    int lane = threadIdx.x & 31;
    int grp  = threadIdx.x >> 5;
    int row  = blockIdx.x * 8 + grp;
    if (row >= N) return;
    float4 v = *(const float4*)(x + (size_t)row * DIM + lane * 4);
    float s = v.x*v.x + v.y*v.y + v.z*v.z + v.w*v.w;
    s += __shfl_xor(s, 16); s += __shfl_xor(s, 8); s += __shfl_xor(s, 4);
    s += __shfl_xor(s, 2);  s += __shfl_xor(s, 1);
    float inv = rsqrtf(s);
    int p = 0;
    p = __builtin_amdgcn_cvt_pk_fp8_f32(v.x * inv, v.y * inv, p, false);
    p = __builtin_amdgcn_cvt_pk_fp8_f32(v.z * inv, v.w * inv, p, true);
    xq[(size_t)row * 32 + lane] = (unsigned int)p;
}

static __device__ __forceinline__ float dot16_fp8(const uint4& r, const float* av) {
    floatx2 t;
    float d = 0.0f;
    t = __builtin_amdgcn_cvt_pk_f32_fp8((int)r.x, false); d += av[0]*t.x  + av[1]*t.y;
    t = __builtin_amdgcn_cvt_pk_f32_fp8((int)r.x, true);  d += av[2]*t.x  + av[3]*t.y;
    t = __builtin_amdgcn_cvt_pk_f32_fp8((int)r.y, false); d += av[4]*t.x  + av[5]*t.y;
    t = __builtin_amdgcn_cvt_pk_f32_fp8((int)r.y, true);  d += av[6]*t.x  + av[7]*t.y;
    t = __builtin_amdgcn_cvt_pk_f32_fp8((int)r.z, false); d += av[8]*t.x  + av[9]*t.y;
    t = __builtin_amdgcn_cvt_pk_f32_fp8((int)r.z, true);  d += av[10]*t.x + av[11]*t.y;
    t = __builtin_amdgcn_cvt_pk_f32_fp8((int)r.w, false); d += av[12]*t.x + av[13]*t.y;
    t = __builtin_amdgcn_cvt_pk_f32_fp8((int)r.w, true);  d += av[14]*t.x + av[15]*t.y;
    return d;
}

// Grid = A*SPLIT blocks; block handles spb=S/SPLIT samples of anchor
// (blockIdx>>2), quarter (blockIdx&3). 256 thr = 32 groups of 8 lanes; lane
// loads uint4 = 16 fp8; 8 lanes cover the 128B row. Each group owns exactly
// 4 samples; ALL FOUR row-gathers are issued into separate named registers
// before any use -> 4 loads in flight per wave (MLP fix; R5 had 1, VGPR=28).
// Prestage packs (sidx<<1)|pos so the inner loop has one LDS read, no y load.
__global__ __launch_bounds__(256, 8) void loss_fp8_kernel(const unsigned int* __restrict__ xq,
                                                          const int* __restrict__ y,
                                                          const int* __restrict__ anchors,
                                                          const int* __restrict__ sampled,
                                                          float* __restrict__ p_num,
                                                          float* __restrict__ p_den,
                                                          float* __restrict__ p_cnt,
                                                          int S) {
    int a    = blockIdx.x >> 2;       // anchor
    int q    = blockIdx.x & 3;        // quarter
    int tid  = threadIdx.x;
    int lane = tid & 7;
    int grp  = tid >> 3;              // 0..31
    int spb  = S >> 2;                // 128 (host guards S==512)

    extern __shared__ int s_pk[];     // [spb]: (sidx<<1) | (y[sidx]==ya)

    int anchor = anchors[a];
    int ya     = y[anchor];

    const int* samp = sampled + (size_t)a * S + (size_t)q * spb;
    for (int i = tid; i < spb; i += 256) {
        int si = samp[i];             // coalesced
        s_pk[i] = (si << 1) | (y[si] == ya ? 1 : 0);  // divergent y gather (L2)
    }

    // anchor row: 16 fp8 -> 16 floats, prescaled by 1/temp
    uint4 ar = *(const uint4*)(xq + (size_t)anchor * 32 + lane * 4);
    float av[16];
    {
        floatx2 t;
        t = __builtin_amdgcn_cvt_pk_f32_fp8((int)ar.x, false); av[0]=t.x;  av[1]=t.y;
        t = __builtin_amdgcn_cvt_pk_f32_fp8((int)ar.x, true);  av[2]=t.x;  av[3]=t.y;
        t = __builtin_amdgcn_cvt_pk_f32_fp8((int)ar.y, false); av[4]=t.x;  av[5]=t.y;
        t = __builtin_amdgcn_cvt_pk_f32_fp8((int)ar.y, true);  av[6]=t.x;  av[7]=t.y;
        t = __builtin_amdgcn_cvt_pk_f32_fp8((int)ar.z, false); av[8]=t.x;  av[9]=t.y;
        t = __builtin_amdgcn_cvt_pk_f32_fp8((int)ar.z, true);  av[10]=t.x; av[11]=t.y;
        t = __builtin_amdgcn_cvt_pk_f32_fp8((int)ar.w, false); av[12]=t.x; av[13]=t.y;
        t = __builtin_amdgcn_cvt_pk_f32_fp8((int)ar.w, true);  av[14]=t.x; av[15]=t.y;
#pragma unroll
        for (int j = 0; j < 16; ++j) av[j] *= TEMP_INV;   // fold 1/temp
    }
    __syncthreads();

    // ---- batch: read 4 packed indices, issue 4 independent row loads ----
    int pk0 = s_pk[grp];
    int pk1 = s_pk[grp + 32];
    int pk2 = s_pk[grp + 64];
    int pk3 = s_pk[grp + 96];

    const uint4* r0p = (const uint4*)(xq + (size_t)(pk0 >> 1) * 32 + lane * 4);
    const uint4* r1p = (const uint4*)(xq + (size_t)(pk1 >> 1) * 32 + lane * 4);
    const uint4* r2p = (const uint4*)(xq + (size_t)(pk2 >> 1) * 32 + lane * 4);
    const uint4* r3p = (const uint4*)(xq + (size_t)(pk3 >> 1) * 32 + lane * 4);
    uint4 r0 = *r0p;
    uint4 r1 = *r1p;
    uint4 r2 = *r2p;
    uint4 r3 = *r3p;

    float num = 0.0f, den = 0.0f, cnt = 0.0f;
    {
        float d = dot16_fp8(r0, av);
        d += __shfl_xor(d, 4); d += __shfl_xor(d, 2); d += __shfl_xor(d, 1);
        float e = __expf(d);
        den += e;
        bool pos = (pk0 & 1);
        num += pos ? e : 0.0f;  cnt += pos ? 1.0f : 0.0f;
    }
    {
        float d = dot16_fp8(r1, av);
        d += __shfl_xor(d, 4); d += __shfl_xor(d, 2); d += __shfl_xor(d, 1);
        float e = __expf(d);
        den += e;
        bool pos = (pk1 & 1);
        num += pos ? e : 0.0f;  cnt += pos ? 1.0f : 0.0f;
    }
    {
        float d = dot16_fp8(r2, av);
        d += __shfl_xor(d, 4); d += __shfl_xor(d, 2); d += __shfl_xor(d, 1);
        float e = __expf(d);
        den += e;
        bool pos = (pk2 & 1);
        num += pos ? e : 0.0f;  cnt += pos ? 1.0f : 0.0f;
    }
    {
        float d = dot16_fp8(r3, av);
        d += __shfl_xor(d, 4); d += __shfl_xor(d, 2); d += __shfl_xor(d, 1);
        float e = __expf(d);
        den += e;
        bool pos = (pk3 & 1);
        num += pos ? e : 0.0f;  cnt += pos ? 1.0f : 0.0f;
    }

    // lanes within an 8-lane group identical; butterfly across the 8 groups
    num += __shfl_xor(num, 8);  den += __shfl_xor(den, 8);  cnt += __shfl_xor(cnt, 8);
    num += __shfl_xor(num, 16); den += __shfl_xor(den, 16); cnt += __shfl_xor(cnt, 16);
    num += __shfl_xor(num, 32); den += __shfl_xor(den, 32); cnt += __shfl_xor(cnt, 32);
    if ((tid & 63) == 0) {
        atomicAdd(p_num + a, num);
        atomicAdd(p_den + a, den);
        atomicAdd(p_cnt + a, cnt);
    }
}

// Per-anchor log + global sum. One thread per anchor.
__global__ __launch_bounds__(256) void finalize_kernel(const float* __restrict__ p_num,
                                                       const float* __restrict__ p_den,
                                                       const float* __restrict__ p_cnt,
                                                       float* __restrict__ out,
                                                       int A) {
    int a = blockIdx.x * 256 + threadIdx.x;
    float loss = 0.0f;
    if (a < A) {
        float tc = p_cnt[a];
        if (tc > 0.0f) loss = -__logf(p_num[a] / p_den[a]) / tc;
    }
    loss += __shfl_xor(loss, 1);  loss += __shfl_xor(loss, 2);
    loss += __shfl_xor(loss, 4);  loss += __shfl_xor(loss, 8);
    loss += __shfl_xor(loss, 16); loss += __shfl_xor(loss, 32);
    if ((threadIdx.x & 63) == 0) atomicAdd(out, loss);
}

// ---------------- fp32 fallback (used only if ws too small / odd shape) -----

__global__ __launch_bounds__(256) void norm_kernel(const float* __restrict__ x,
                                                   float* __restrict__ inv_norm,
                                                   float* __restrict__ out,
                                                   int N) {
    if (blockIdx.x == 0 && threadIdx.x == 0) out[0] = 0.0f;
    int wave = threadIdx.x >> 6;
    int lane = threadIdx.x & 63;
    int row  = blockIdx.x * 4 + wave;
    if (row >= N) return;
    const float2 v = *(const float2*)(x + (size_t)row * DIM + lane * 2);
    float s = v.x * v.x + v.y * v.y;
    s += __shfl_xor(s, 32); s += __shfl_xor(s, 16); s += __shfl_xor(s, 8);
    s += __shfl_xor(s, 4);  s += __shfl_xor(s, 2);  s += __shfl_xor(s, 1);
    if (lane == 0) inv_norm[row] = rsqrtf(s);
}

__global__ __launch_bounds__(256) void loss_kernel(const float* __restrict__ x,
                                                   const int* __restrict__ y,
                                                   const int* __restrict__ anchors,
                                                   const int* __restrict__ sampled,
                                                   const float* __restrict__ inv_norm,
                                                   float* __restrict__ out,
                                                   int S) {
    int a     = blockIdx.x;
    int tid   = threadIdx.x;
    int lane  = tid & 31;
    int group = tid >> 5;

    int   anchor = anchors[a];
    int   ya     = y[anchor];
    float inv_a  = inv_norm[anchor];
    float4 av = *(const float4*)(x + (size_t)anchor * DIM + lane * 4);
    av.x *= inv_a; av.y *= inv_a; av.z *= inv_a; av.w *= inv_a;

    float num = 0.0f, den = 0.0f, cnt = 0.0f;
    const int* samp = sampled + (size_t)a * S;

#pragma unroll 4
    for (int s = group; s < S; s += 8) {
        int   sidx  = samp[s];
        float inv_s = inv_norm[sidx];
        int   ys    = y[sidx];
        const float4 sv = *(const float4*)(x + (size_t)sidx * DIM + lane * 4);
        float d = av.x * sv.x + av.y * sv.y + av.z * sv.z + av.w * sv.w;
        d += __shfl_xor(d, 16); d += __shfl_xor(d, 8); d += __shfl_xor(d, 4);
        d += __shfl_xor(d, 2);  d += __shfl_xor(d, 1);
        float e = __expf(d * inv_s * TEMP_INV);
        den += e;
        bool pos = (ys == ya);
        num += pos ? e : 0.0f;
        cnt += pos ? 1.0f : 0.0f;
    }

    __shared__ float s_num[8], s_den[8], s_cnt[8];
    if (lane == 0) { s_num[group] = num; s_den[group] = den; s_cnt[group] = cnt; }
    __syncthreads();
    if (tid == 0) {
        float tn = 0.0f, td = 0.0f, tc = 0.0f;
        for (int g = 0; g < 8; ++g) { tn += s_num[g]; td += s_den[g]; tc += s_cnt[g]; }
        float loss = 0.0f;
        if (tc > 0.0f) loss = -__logf(tn / td) / tc;
        atomicAdd(out, loss);
    }
}

extern "C" void kernel_launch(void* const* d_in, const int* in_sizes, int n_in,
                              void* d_out, int out_size, void* d_ws, size_t ws_size,
                              hipStream_t stream) {
    const float* x       = (const float*)d_in[0];
    const int*   y       = (const int*)d_in[1];
    const int*   anchors = (const int*)d_in[2];
    const int*   sampled = (const int*)d_in[3];

    int N = in_sizes[1];
    int A = in_sizes[2];
    int S = in_sizes[3] / A;

    float* out = (float*)d_out;
    size_t need_fp8 = (size_t)N * DIM + (size_t)3 * A * sizeof(float);

    if (ws_size >= need_fp8 && S == 512) {
        unsigned int* xq = (unsigned int*)d_ws;
        float* partials  = (float*)((char*)d_ws + (size_t)N * DIM);
        float* p_num = partials;
        float* p_den = partials + A;
        float* p_cnt = partials + 2 * A;

        int nblocks = (N + 7) / 8;
        norm_fp8_kernel<<<nblocks, 256, 0, stream>>>(x, xq, partials, 3 * A, out, N);
        int spb = S / SPLIT;                       // 128
        size_t lds = (size_t)spb * sizeof(int);
        loss_fp8_kernel<<<A * SPLIT, 256, lds, stream>>>(xq, y, anchors, sampled,
                                                         p_num, p_den, p_cnt, S);
        finalize_kernel<<<(A + 255) / 256, 256, 0, stream>>>(p_num, p_den, p_cnt, out, A);
    } else {
        float* inv_norm = (float*)d_ws;
        int nblocks = (N + 3) / 4;
        norm_kernel<<<nblocks, 256, 0, stream>>>(x, inv_norm, out, N);
        loss_kernel<<<A, 256, 0, stream>>>(x, y, anchors, sampled, inv_norm, out, S);
    }
}